// Round 1
// baseline (114.462 us; speedup 1.0000x reference)
//
#include <hip/hip_runtime.h>
#include <math.h>

// Fused single-kernel version.
// - Per 256-thread block (4 waves = 4 rays): the 5 segment boundaries
//   bnd[j] = lower_bound(ray_id, r0+j) are found in-kernel by a
//   wave-cooperative 64-ary search (4 probe loads per search; round-1 probes
//   are identical chip-wide -> L1/L2 hot). This removes the seg_starts
//   kernel, its 16 MB ray_id sweep, the starts[] HBM round-trip, and the
//   inter-kernel serialization bubble.
// - March loop: 4 samples/lane, 256-sample chunks. Lanes fully past `end`
//   skip their loads (exec-masked, re-converged before the scan) -> no
//   tail over-fetch. Invalid samples get density -1e30 -> om=1, w=0.
// - All cross-lane ops are DPP (VALU-speed): wave64 inclusive cumprod =
//   row_shr:1,2,4,8 + row_bcast:15 + row_bcast:31; exclusive shift =
//   wave_shr:1 with old=identity; lane-63 broadcast = v_readlane.
// - Math: om = exp(-0.5*softplus(x)) = rsqrt(1+exp(x)); alpha = 1-om.
//   out[r] = sum w_i * sigmoid(rgb_i) + alphainv_last (white background).

__device__ __forceinline__ float sigm(float x) {
    return __builtin_amdgcn_rcpf(1.0f + __expf(-x));
}

// DPP helpers: old = identity so shifted-in / masked-off rows contribute
// the identity element (bound_ctrl=false keeps `old` for invalid lanes).
template <int Ctrl, int RowMask>
__device__ __forceinline__ float dpp_mul(float x) {
    const int s = __builtin_amdgcn_update_dpp(
        __float_as_int(1.0f), __float_as_int(x), Ctrl, RowMask, 0xf, false);
    return x * __int_as_float(s);
}
template <int Ctrl, int RowMask>
__device__ __forceinline__ float dpp_add(float x) {
    const int s = __builtin_amdgcn_update_dpp(
        __float_as_int(0.0f), __float_as_int(x), Ctrl, RowMask, 0xf, false);
    return x + __int_as_float(s);
}

// wave64 inclusive scans (result on lane i = op over lanes 0..i)
__device__ __forceinline__ float wave_cumprod(float p) {
    p = dpp_mul<0x111, 0xf>(p);   // row_shr:1
    p = dpp_mul<0x112, 0xf>(p);   // row_shr:2
    p = dpp_mul<0x114, 0xf>(p);   // row_shr:4
    p = dpp_mul<0x118, 0xf>(p);   // row_shr:8
    p = dpp_mul<0x142, 0xa>(p);   // row_bcast:15 -> rows 1,3
    p = dpp_mul<0x143, 0xc>(p);   // row_bcast:31 -> rows 2,3
    return p;
}
__device__ __forceinline__ float wave_cumsum(float a) {
    a = dpp_add<0x111, 0xf>(a);
    a = dpp_add<0x112, 0xf>(a);
    a = dpp_add<0x114, 0xf>(a);
    a = dpp_add<0x118, 0xf>(a);
    a = dpp_add<0x142, 0xa>(a);
    a = dpp_add<0x143, 0xc>(a);
    return a;
}
__device__ __forceinline__ float lane63(float x) {
    return __int_as_float(__builtin_amdgcn_readlane(__float_as_int(x), 63));
}

// Wave-cooperative lower_bound over a globally sorted int array.
// Returns first index i with a[i] >= target (or n). 64-ary narrowing:
// n=4.19M -> <=65535 -> <=1023 -> <=15 -> exact. 4 probe loads total.
// pred is monotone (array sorted), so popcount(ballot) locates the edge.
__device__ __forceinline__ int wave_lower_bound(const int* __restrict__ a,
                                                int n, int target, int lane)
{
    int lo = 0, hi = n;
    while (hi - lo > 64) {
        const int step = ((hi - lo) + 63) >> 6;      // ceil(len/64)
        const int pos  = lo + lane * step;
        const bool pred = (pos < n) && (a[pos] < target);
        const int cnt = __popcll(__ballot(pred));
        if (cnt == 0) break;                          // lb == lo exactly
        const int nhi = lo + cnt * step;              // first false probe
        lo = lo + (cnt - 1) * step + 1;               // last true probe + 1
        hi = min(hi, nhi);
    }
    // final round, step = 1: indices >= old hi are >= target by sortedness,
    // so counting over [lo, lo+64) is safe.
    const int pos = lo + lane;
    const bool pred = (pos < n) && (a[pos] < target);
    return lo + __popcll(__ballot(pred));
}

__global__ __launch_bounds__(256) void fused_march_kernel(
    const float* __restrict__ density,
    const float* __restrict__ rgb_raw,
    const float* __restrict__ shift,
    const int*   __restrict__ ray_id,
    float* __restrict__ out,
    int M, int N)
{
    __shared__ int bnd[5];
    const int lane = threadIdx.x & 63;
    const int wave = threadIdx.x >> 6;
    const int r0   = blockIdx.x * 4;

    // 5 boundaries for rays r0..r0+3 (bnd[4] = end of ray r0+3).
    // wave w finds bnd[w]; wave 0 additionally finds bnd[4].
    {
        const int b = wave_lower_bound(ray_id, M, r0 + wave, lane);
        if (lane == 0) bnd[wave] = b;
        if (wave == 0) {
            const int b4 = wave_lower_bound(ray_id, M, r0 + 4, lane);
            if (lane == 0) bnd[4] = b4;
        }
    }
    __syncthreads();

    const int ray = r0 + wave;
    if (ray >= N) return;

    const float sh   = shift[0];
    const int begin  = bnd[wave];
    const int end    = bnd[wave + 1];

    float carry = 1.0f;
    float acc0 = 0.0f, acc1 = 0.0f, acc2 = 0.0f;

    for (int base = (begin & ~3); base < end; base += 256) {
        const int b4 = base + 4 * lane;

        float d0 = -1e30f, d1 = -1e30f, d2 = -1e30f, d3 = -1e30f;
        float4 c0 = {0.f, 0.f, 0.f, 0.f};
        float4 c1 = {0.f, 0.f, 0.f, 0.f};
        float4 c2 = {0.f, 0.f, 0.f, 0.f};

        if (b4 < end) {                       // tail lanes skip loads entirely
            const int ba = min(b4, M - 4);    // M % 4 == 0 -> ba == b4 when valid
            const float4 dd = *(const float4*)(density + ba);
            const float4* rp = (const float4*)(rgb_raw + 3 * ba);
            c0 = rp[0]; c1 = rp[1]; c2 = rp[2];

            const bool v0 = (b4 + 0 >= begin);
            const bool v1 = (b4 + 1 >= begin) & (b4 + 1 < end);
            const bool v2 = (b4 + 2 >= begin) & (b4 + 2 < end);
            const bool v3 = (b4 + 3 >= begin) & (b4 + 3 < end);
            d0 = v0 ? dd.x : -1e30f;
            d1 = v1 ? dd.y : -1e30f;
            d2 = v2 ? dd.z : -1e30f;
            d3 = v3 ? dd.w : -1e30f;
        }
        // all lanes re-converged here: scan must see 64 active lanes

        const float om0 = __builtin_amdgcn_rsqf(1.0f + __expf(d0 + sh));
        const float om1 = __builtin_amdgcn_rsqf(1.0f + __expf(d1 + sh));
        const float om2 = __builtin_amdgcn_rsqf(1.0f + __expf(d2 + sh));
        const float om3 = __builtin_amdgcn_rsqf(1.0f + __expf(d3 + sh));
        const float al0 = 1.0f - om0, al1 = 1.0f - om1;
        const float al2 = 1.0f - om2, al3 = 1.0f - om3;

        // wave-wide inclusive cumprod over lane products (pure DPP/VALU)
        const float p = wave_cumprod((om0 * om1) * (om2 * om3));

        // exclusive prefix: wave_shr:1, lane0 gets identity (old=1.0)
        const float excl = __int_as_float(__builtin_amdgcn_update_dpp(
            __float_as_int(1.0f), __float_as_int(p), 0x138, 0xf, 0xf, false));

        float t = carry * excl;
        const float w0 = al0 * t; t *= om0;
        const float w1 = al1 * t; t *= om1;
        const float w2 = al2 * t; t *= om2;
        const float w3 = al3 * t;

        acc0 += w0 * sigm(c0.x) + w1 * sigm(c0.w) + w2 * sigm(c1.z) + w3 * sigm(c2.y);
        acc1 += w0 * sigm(c0.y) + w1 * sigm(c1.x) + w2 * sigm(c1.w) + w3 * sigm(c2.z);
        acc2 += w0 * sigm(c0.z) + w1 * sigm(c1.y) + w2 * sigm(c2.x) + w3 * sigm(c2.w);

        carry *= lane63(p);       // chunk product broadcast (VALU readlane)
    }

    // epilogue: channel totals via DPP scan, total lives on lane 63
    const float tot0 = lane63(wave_cumsum(acc0));
    const float tot1 = lane63(wave_cumsum(acc1));
    const float tot2 = lane63(wave_cumsum(acc2));

    if (lane == 0) {
        out[3 * ray + 0] = tot0 + carry;   // + alphainv_last
        out[3 * ray + 1] = tot1 + carry;
        out[3 * ray + 2] = tot2 + carry;
    }
}

extern "C" void kernel_launch(void* const* d_in, const int* in_sizes, int n_in,
                              void* d_out, int out_size, void* d_ws, size_t ws_size,
                              hipStream_t stream)
{
    const float* density = (const float*)d_in[0];
    const float* rgb_raw = (const float*)d_in[1];
    const float* shift   = (const float*)d_in[2];
    const int*   ray_id  = (const int*)d_in[3];
    float* out = (float*)d_out;

    const int M = in_sizes[0];
    const int N = out_size / 3;

    const int blocks = (N + 3) / 4;    // 4 rays (waves) per 256-thread block
    fused_march_kernel<<<blocks, 256, 0, stream>>>(density, rgb_raw, shift,
                                                   ray_id, out, M, N);
}

// Round 2
// 113.706 us; speedup vs baseline: 1.0066x; 1.0066x over previous
//
#include <hip/hip_runtime.h>
#include <math.h>

// Two-kernel structure (proven correct in R0), march re-granularized:
// k1 (seg_starts): starts[r] = first sample index of ray r, starts[N] = M.
//     int4-vectorized coalesced pass over ray_id.
// k2 (voxel_march): one wave per ray (4 rays / 256-thread block), ONE sample
//     per lane, 64-sample chunks:
//       - base = begin exactly (scalar loads, no alignment waste at head)
//       - tail over-fetch <= 63 samples/ray (avg ~32) vs ~128 at chunk=256
//       - loads unconditional + address-clamped (no divergent guard; the
//         whole-chunk skip test `nb < end` is wave-uniform)
//       - 2-deep software pipeline: next chunk's loads issue before current
//         chunk's compute -> MLP preserved across the short loop
// All cross-lane ops are DPP (VALU-speed): wave64 inclusive cumprod =
//     row_shr:1,2,4,8 + row_bcast:15 + row_bcast:31; exclusive shift =
//     wave_shr:1 with old=identity; lane-63 broadcast = v_readlane.
// Math: om = exp(-0.5*softplus(x)) = rsqrt(1+exp(x)); alpha = 1-om.
// out[r] = sum w_i * sigmoid(rgb_i) + alphainv_last (white background).

__device__ __forceinline__ float sigm(float x) {
    return __builtin_amdgcn_rcpf(1.0f + __expf(-x));
}

// DPP helpers: old = identity so shifted-in / masked-off rows contribute
// the identity element (bound_ctrl=false keeps `old` for invalid lanes).
template <int Ctrl, int RowMask>
__device__ __forceinline__ float dpp_mul(float x) {
    const int s = __builtin_amdgcn_update_dpp(
        __float_as_int(1.0f), __float_as_int(x), Ctrl, RowMask, 0xf, false);
    return x * __int_as_float(s);
}
template <int Ctrl, int RowMask>
__device__ __forceinline__ float dpp_add(float x) {
    const int s = __builtin_amdgcn_update_dpp(
        __float_as_int(0.0f), __float_as_int(x), Ctrl, RowMask, 0xf, false);
    return x + __int_as_float(s);
}

// wave64 inclusive scans (result on lane i = op over lanes 0..i)
__device__ __forceinline__ float wave_cumprod(float p) {
    p = dpp_mul<0x111, 0xf>(p);   // row_shr:1
    p = dpp_mul<0x112, 0xf>(p);   // row_shr:2
    p = dpp_mul<0x114, 0xf>(p);   // row_shr:4
    p = dpp_mul<0x118, 0xf>(p);   // row_shr:8
    p = dpp_mul<0x142, 0xa>(p);   // row_bcast:15 -> rows 1,3
    p = dpp_mul<0x143, 0xc>(p);   // row_bcast:31 -> rows 2,3
    return p;
}
__device__ __forceinline__ float wave_cumsum(float a) {
    a = dpp_add<0x111, 0xf>(a);
    a = dpp_add<0x112, 0xf>(a);
    a = dpp_add<0x114, 0xf>(a);
    a = dpp_add<0x118, 0xf>(a);
    a = dpp_add<0x142, 0xa>(a);
    a = dpp_add<0x143, 0xc>(a);
    return a;
}
__device__ __forceinline__ float lane63(float x) {
    return __int_as_float(__builtin_amdgcn_readlane(__float_as_int(x), 63));
}

__global__ __launch_bounds__(256) void seg_starts_kernel(
    const int* __restrict__ ray_id, int* __restrict__ starts, int M, int N)
{
    const int i4 = (blockIdx.x * 256 + threadIdx.x) * 4;
    if (i4 >= M) return;

    if (i4 + 3 < M) {
        const int4 v = *(const int4*)(ray_id + i4);
        const int prev = (i4 == 0) ? -1 : ray_id[i4 - 1];
        for (int r = prev + 1; r <= v.x; ++r) starts[r] = i4 + 0;
        for (int r = v.x + 1; r <= v.y; ++r) starts[r] = i4 + 1;
        for (int r = v.y + 1; r <= v.z; ++r) starts[r] = i4 + 2;
        for (int r = v.z + 1; r <= v.w; ++r) starts[r] = i4 + 3;
        if (i4 + 4 == M) {
            for (int r = v.w + 1; r <= N; ++r) starts[r] = M;  // tail + sentinel
        }
    } else {
        int prev = (i4 == 0) ? -1 : ray_id[i4 - 1];
        for (int k = 0; k < 4 && i4 + k < M; ++k) {
            const int cur = ray_id[i4 + k];
            for (int r = prev + 1; r <= cur; ++r) starts[r] = i4 + k;
            prev = cur;
            if (i4 + k == M - 1)
                for (int r = cur + 1; r <= N; ++r) starts[r] = M;
        }
    }
}

__global__ __launch_bounds__(256) void voxel_march_kernel(
    const float* __restrict__ density,
    const float* __restrict__ rgb_raw,
    const float* __restrict__ shift,
    const int*   __restrict__ starts,
    float* __restrict__ out,
    int M, int N)
{
    const int lane = threadIdx.x & 63;
    const int wave = threadIdx.x >> 6;
    const int ray  = blockIdx.x * 4 + wave;
    if (ray >= N) return;

    const float sh = shift[0];
    const int begin = starts[ray];
    const int end   = starts[ray + 1];

    float carry = 1.0f;
    float acc0 = 0.0f, acc1 = 0.0f, acc2 = 0.0f;

    // prologue: load chunk 0 (dense, clamped, then masked)
    float dcur = -1e30f, c0 = 0.0f, c1 = 0.0f, c2 = 0.0f;
    if (begin < end) {                       // wave-uniform
        const int g  = begin + lane;
        const int gc = min(g, M - 1);
        dcur = density[gc];
        c0 = rgb_raw[3 * gc + 0];
        c1 = rgb_raw[3 * gc + 1];
        c2 = rgb_raw[3 * gc + 2];
        if (g >= end) dcur = -1e30f;         // invalid -> om=1, w=0
    }

    for (int base = begin; base < end; base += 64) {
        // issue next chunk's loads before computing this chunk (2-deep pipe)
        float dnx = -1e30f, n0 = 0.0f, n1 = 0.0f, n2 = 0.0f;
        const int nb = base + 64;
        if (nb < end) {                      // wave-uniform
            const int g  = nb + lane;
            const int gc = min(g, M - 1);
            dnx = density[gc];
            n0 = rgb_raw[3 * gc + 0];
            n1 = rgb_raw[3 * gc + 1];
            n2 = rgb_raw[3 * gc + 2];
            if (g >= end) dnx = -1e30f;
        }

        const float om = __builtin_amdgcn_rsqf(1.0f + __expf(dcur + sh));
        const float al = 1.0f - om;

        // wave-wide inclusive cumprod (pure DPP/VALU)
        const float p = wave_cumprod(om);
        // exclusive prefix: wave_shr:1, lane0 gets identity (old=1.0)
        const float excl = __int_as_float(__builtin_amdgcn_update_dpp(
            __float_as_int(1.0f), __float_as_int(p), 0x138, 0xf, 0xf, false));

        const float w = al * (carry * excl);
        acc0 += w * sigm(c0);
        acc1 += w * sigm(c1);
        acc2 += w * sigm(c2);

        carry *= lane63(p);                  // chunk product broadcast

        dcur = dnx; c0 = n0; c1 = n1; c2 = n2;
    }

    // epilogue: channel totals via DPP scan, total lives on lane 63
    const float tot0 = lane63(wave_cumsum(acc0));
    const float tot1 = lane63(wave_cumsum(acc1));
    const float tot2 = lane63(wave_cumsum(acc2));

    if (lane == 0) {
        out[3 * ray + 0] = tot0 + carry;   // + alphainv_last
        out[3 * ray + 1] = tot1 + carry;
        out[3 * ray + 2] = tot2 + carry;
    }
}

extern "C" void kernel_launch(void* const* d_in, const int* in_sizes, int n_in,
                              void* d_out, int out_size, void* d_ws, size_t ws_size,
                              hipStream_t stream)
{
    const float* density = (const float*)d_in[0];
    const float* rgb_raw = (const float*)d_in[1];
    const float* shift   = (const float*)d_in[2];
    const int*   ray_id  = (const int*)d_in[3];
    float* out = (float*)d_out;

    const int M = in_sizes[0];
    const int N = out_size / 3;

    int* starts = (int*)d_ws;
    const int t1 = (M + 3) / 4;
    seg_starts_kernel<<<(t1 + 255) / 256, 256, 0, stream>>>(ray_id, starts, M, N);

    const int rays_per_block = 4;
    const int blocks = (N + rays_per_block - 1) / rays_per_block;
    voxel_march_kernel<<<blocks, 256, 0, stream>>>(density, rgb_raw, shift,
                                                   starts, out, M, N);
}

// Round 3
// 111.926 us; speedup vs baseline: 1.0227x; 1.0159x over previous
//
#include <hip/hip_runtime.h>
#include <math.h>

// k1 (seg_starts): starts[r] = first sample index of ray r, starts[N] = M.
//     int4-vectorized coalesced pass over ray_id (BW-minimal: 16 MB read).
// k2 (voxel_march): TWO rays per wave (32 lanes/ray), 4 samples/lane,
//     128-sample chunks, float4 loads:
//       - same VMEM-instruction rate as the chunk=256 version (1 load / 4
//         samples) -> no issue-overhead regression (R2 lesson)
//       - tail over-fetch halved vs chunk=256 (~17 MB less L2 re-read)
//       - scan = two independent 32-lane DPP cumprods (drop row_bcast:31);
//         exclusive shift = wave_shr:1 + cndmask identity at lane 0/32;
//         per-half carry via readlane(31)/readlane(63) + select.
//     Half-wave divergence on ray length is safe: each half's DPP ops only
//     source lanes within that half (active); readlane ignores exec.
// Math: om = exp(-0.5*softplus(x)) = rsqrt(1+exp(x)); alpha = 1-om.
// out[r] = sum w_i * sigmoid(rgb_i) + alphainv_last (white background).

__device__ __forceinline__ float sigm(float x) {
    return __builtin_amdgcn_rcpf(1.0f + __expf(-x));
}

// DPP helpers: old = identity so shifted-in / masked-off rows contribute
// the identity element (bound_ctrl=false keeps `old` for invalid lanes).
template <int Ctrl, int RowMask>
__device__ __forceinline__ float dpp_mul(float x) {
    const int s = __builtin_amdgcn_update_dpp(
        __float_as_int(1.0f), __float_as_int(x), Ctrl, RowMask, 0xf, false);
    return x * __int_as_float(s);
}
template <int Ctrl, int RowMask>
__device__ __forceinline__ float dpp_add(float x) {
    const int s = __builtin_amdgcn_update_dpp(
        __float_as_int(0.0f), __float_as_int(x), Ctrl, RowMask, 0xf, false);
    return x + __int_as_float(s);
}

// Independent 32-lane inclusive scans in each half-wave:
// row_shr:1,2,4,8 build 16-lane row scans; row_bcast:15 (rows 1,3) folds
// row 0 into row 1 and row 2 into row 3. No row_bcast:31 -> halves stay
// independent. Result: lane i has op over lanes (i & ~31)..i.
__device__ __forceinline__ float half_cumprod(float p) {
    p = dpp_mul<0x111, 0xf>(p);   // row_shr:1
    p = dpp_mul<0x112, 0xf>(p);   // row_shr:2
    p = dpp_mul<0x114, 0xf>(p);   // row_shr:4
    p = dpp_mul<0x118, 0xf>(p);   // row_shr:8
    p = dpp_mul<0x142, 0xa>(p);   // row_bcast:15 -> rows 1,3
    return p;
}
__device__ __forceinline__ float half_cumsum(float a) {
    a = dpp_add<0x111, 0xf>(a);
    a = dpp_add<0x112, 0xf>(a);
    a = dpp_add<0x114, 0xf>(a);
    a = dpp_add<0x118, 0xf>(a);
    a = dpp_add<0x142, 0xa>(a);
    return a;
}
__device__ __forceinline__ float rdlane(float x, int l) {
    return __int_as_float(__builtin_amdgcn_readlane(__float_as_int(x), l));
}

__global__ __launch_bounds__(256) void seg_starts_kernel(
    const int* __restrict__ ray_id, int* __restrict__ starts, int M, int N)
{
    const int i4 = (blockIdx.x * 256 + threadIdx.x) * 4;
    if (i4 >= M) return;

    if (i4 + 3 < M) {
        const int4 v = *(const int4*)(ray_id + i4);
        const int prev = (i4 == 0) ? -1 : ray_id[i4 - 1];
        for (int r = prev + 1; r <= v.x; ++r) starts[r] = i4 + 0;
        for (int r = v.x + 1; r <= v.y; ++r) starts[r] = i4 + 1;
        for (int r = v.y + 1; r <= v.z; ++r) starts[r] = i4 + 2;
        for (int r = v.z + 1; r <= v.w; ++r) starts[r] = i4 + 3;
        if (i4 + 4 == M) {
            for (int r = v.w + 1; r <= N; ++r) starts[r] = M;  // tail + sentinel
        }
    } else {
        int prev = (i4 == 0) ? -1 : ray_id[i4 - 1];
        for (int k = 0; k < 4 && i4 + k < M; ++k) {
            const int cur = ray_id[i4 + k];
            for (int r = prev + 1; r <= cur; ++r) starts[r] = i4 + k;
            prev = cur;
            if (i4 + k == M - 1)
                for (int r = cur + 1; r <= N; ++r) starts[r] = M;
        }
    }
}

__global__ __launch_bounds__(256) void voxel_march_kernel(
    const float* __restrict__ density,
    const float* __restrict__ rgb_raw,
    const float* __restrict__ shift,
    const int*   __restrict__ starts,
    float* __restrict__ out,
    int M, int N)
{
    const int lane = threadIdx.x & 63;
    const int l32  = lane & 31;
    const int wave = threadIdx.x >> 6;
    const int ray  = blockIdx.x * 8 + wave * 2 + (lane >> 5);
    const bool ray_ok = (ray < N);

    const float sh = shift[0];
    int begin = 0, end = 0;
    if (ray_ok) {
        begin = starts[ray];
        end   = starts[ray + 1];
    }

    float carry = 1.0f;
    float acc0 = 0.0f, acc1 = 0.0f, acc2 = 0.0f;

    for (int base = (begin & ~3); base < end; base += 128) {
        const int b4 = base + 4 * l32;
        const int ba = min(b4, M - 4);           // address-safe clamp

        const float4 dd = *(const float4*)(density + ba);
        const float4* rp = (const float4*)(rgb_raw + 3 * ba);
        const float4 c0 = rp[0], c1 = rp[1], c2 = rp[2];

        const bool v0 = (b4 + 0 >= begin) & (b4 + 0 < end);
        const bool v1 = (b4 + 1 >= begin) & (b4 + 1 < end);
        const bool v2 = (b4 + 2 >= begin) & (b4 + 2 < end);
        const bool v3 = (b4 + 3 >= begin) & (b4 + 3 < end);
        const float d0 = v0 ? dd.x : -1e30f;     // invalid -> om=1, w=0
        const float d1 = v1 ? dd.y : -1e30f;
        const float d2 = v2 ? dd.z : -1e30f;
        const float d3 = v3 ? dd.w : -1e30f;

        const float om0 = __builtin_amdgcn_rsqf(1.0f + __expf(d0 + sh));
        const float om1 = __builtin_amdgcn_rsqf(1.0f + __expf(d1 + sh));
        const float om2 = __builtin_amdgcn_rsqf(1.0f + __expf(d2 + sh));
        const float om3 = __builtin_amdgcn_rsqf(1.0f + __expf(d3 + sh));
        const float al0 = 1.0f - om0, al1 = 1.0f - om1;
        const float al2 = 1.0f - om2, al3 = 1.0f - om3;

        // two independent 32-lane inclusive cumprods over lane products
        const float p = half_cumprod((om0 * om1) * (om2 * om3));

        // exclusive prefix: wave_shr:1; lanes 0 and 32 need identity
        // (lane 0 gets old=1.0 from bound_ctrl; lane 32 gets lane31 -> patch)
        float excl = __int_as_float(__builtin_amdgcn_update_dpp(
            __float_as_int(1.0f), __float_as_int(p), 0x138, 0xf, 0xf, false));
        excl = (l32 == 0) ? 1.0f : excl;

        float t = carry * excl;
        const float w0 = al0 * t; t *= om0;
        const float w1 = al1 * t; t *= om1;
        const float w2 = al2 * t; t *= om2;
        const float w3 = al3 * t;

        acc0 += w0 * sigm(c0.x) + w1 * sigm(c0.w) + w2 * sigm(c1.z) + w3 * sigm(c2.y);
        acc1 += w0 * sigm(c0.y) + w1 * sigm(c1.x) + w2 * sigm(c1.w) + w3 * sigm(c2.z);
        acc2 += w0 * sigm(c0.z) + w1 * sigm(c1.y) + w2 * sigm(c2.x) + w3 * sigm(c2.w);

        // per-half chunk product broadcast (readlane ignores exec; each
        // active lane selects its own half's product)
        const float cA = rdlane(p, 31);
        const float cB = rdlane(p, 63);
        carry *= (lane < 32) ? cA : cB;
    }

    // epilogue (halves reconverged): per-half channel totals via DPP scan;
    // ray A total on lane 31, ray B total on lane 63.
    const float s0 = half_cumsum(acc0);
    const float s1 = half_cumsum(acc1);
    const float s2 = half_cumsum(acc2);
    const float t0 = (lane < 32) ? rdlane(s0, 31) : rdlane(s0, 63);
    const float t1 = (lane < 32) ? rdlane(s1, 31) : rdlane(s1, 63);
    const float t2 = (lane < 32) ? rdlane(s2, 31) : rdlane(s2, 63);

    if (ray_ok && l32 == 0) {
        out[3 * ray + 0] = t0 + carry;   // + alphainv_last
        out[3 * ray + 1] = t1 + carry;
        out[3 * ray + 2] = t2 + carry;
    }
}

extern "C" void kernel_launch(void* const* d_in, const int* in_sizes, int n_in,
                              void* d_out, int out_size, void* d_ws, size_t ws_size,
                              hipStream_t stream)
{
    const float* density = (const float*)d_in[0];
    const float* rgb_raw = (const float*)d_in[1];
    const float* shift   = (const float*)d_in[2];
    const int*   ray_id  = (const int*)d_in[3];
    float* out = (float*)d_out;

    const int M = in_sizes[0];
    const int N = out_size / 3;

    int* starts = (int*)d_ws;
    const int t1 = (M + 3) / 4;
    seg_starts_kernel<<<(t1 + 255) / 256, 256, 0, stream>>>(ray_id, starts, M, N);

    const int rays_per_block = 8;   // 2 rays per wave, 4 waves per block
    const int blocks = (N + rays_per_block - 1) / rays_per_block;
    voxel_march_kernel<<<blocks, 256, 0, stream>>>(density, rgb_raw, shift,
                                                   starts, out, M, N);
}

// Round 4
// 109.314 us; speedup vs baseline: 1.0471x; 1.0239x over previous
//
#include <hip/hip_runtime.h>
#include <math.h>

// R4: dense-tile segmented scan, two kernels.
//
// k1 (march_dense): grid covers samples 0..M densely. Each WAVE owns a fixed
//   256-sample chunk (4 samples/lane): int4 ray_id + float4 density + 3x
//   float4 rgb -> zero over-fetch, no starts[] dependency, perfect balance.
//   Within a chunk, rays are segments; per-sample transmittance and per-
//   segment weighted-rgb sums are computed with a wave-level SEGMENTED
//   AFFINE scan in DPP registers:
//       element  = (p, s0, s1, s2, f)   p: prod(om), s: sum(w*sigm), f: cut
//       combine(A,B) = B.f ? B : (pA*pB, sA + pA*sB, fA|fB)
//   (associative -> valid on the Hillis-Steele DPP network row_shr:1,2,4,8 +
//   row_bcast:15 + row_bcast:31; identity (1,0,0,0,0) injected at row edges
//   via the dpp `old` operand.)
//   Rays fully inside a chunk -> written directly. Chunk head/tail pieces ->
//   records (sum3,prod) + (firstID,lastID) in workspace. Gaps (empty rays)
//   white-filled at boundary detection.
// k2 (stitch): one thread per chunk boundary (C+1 total). Combines straddling
//   ray pieces with a short backward walk over tail records:
//       cs = S_j + P_j*cs ; cp *= P_j    (right-nested affine combine)
//   writes out = cs + cp (white background). Handles rays ending exactly at
//   chunk boundaries, rays starting exactly at chunk starts, global edges,
//   and empty-ray white fill. Max ray len (~330) << 512 so walks are short;
//   the walk loop is fully general regardless.
//
// Math identical to R0..R3: om = rsqrt(1+exp(d+sh)); al = 1-om;
// sigm = rcp(1+exp(-x)); out[r] = sum w_i*sigm(rgb_i) + alphainv_last.
// Assumes M % 256 == 0 (benchmark: M = 4194304).

#define CHUNK 256

__device__ __forceinline__ float sigm(float x) {
    return __builtin_amdgcn_rcpf(1.0f + __expf(-x));
}

template <int Ctrl, int RowMask>
__device__ __forceinline__ float dpp_movf(float x, float old) {
    return __int_as_float(__builtin_amdgcn_update_dpp(
        __float_as_int(old), __float_as_int(x), Ctrl, RowMask, 0xf, false));
}
template <int Ctrl, int RowMask>
__device__ __forceinline__ int dpp_movi(int x, int old) {
    return __builtin_amdgcn_update_dpp(old, x, Ctrl, RowMask, 0xf, false);
}

struct Seg { float p, s0, s1, s2; int f; };

// one scan step: combine(prev_from_dpp, cur). Masked-off / row-edge lanes
// receive the identity (1,0,0,0,0) via `old` -> value unchanged.
template <int Ctrl, int RowMask>
__device__ __forceinline__ void seg_step(Seg& a) {
    const float pp = dpp_movf<Ctrl, RowMask>(a.p, 1.0f);
    const float t0 = dpp_movf<Ctrl, RowMask>(a.s0, 0.0f);
    const float t1 = dpp_movf<Ctrl, RowMask>(a.s1, 0.0f);
    const float t2 = dpp_movf<Ctrl, RowMask>(a.s2, 0.0f);
    const int   ff = dpp_movi<Ctrl, RowMask>(a.f, 0);
    const bool cut = (a.f != 0);
    const float pa = cut ? 1.0f : pp;      // prev prod unless cur has a cut
    a.s0 = fmaf(pa, a.s0, cut ? 0.0f : t0);
    a.s1 = fmaf(pa, a.s1, cut ? 0.0f : t1);
    a.s2 = fmaf(pa, a.s2, cut ? 0.0f : t2);
    a.p  = pa * a.p;
    a.f  = a.f | ff;
}

__global__ __launch_bounds__(256) void march_dense_kernel(
    const float* __restrict__ density,
    const float* __restrict__ rgb_raw,
    const float* __restrict__ shift,
    const int*   __restrict__ ray_id,
    float* __restrict__ out,
    int2*   __restrict__ ids,
    float4* __restrict__ head,
    float4* __restrict__ tail,
    int C)
{
    const int lane = threadIdx.x & 63;
    const int wave = threadIdx.x >> 6;
    const int c    = blockIdx.x * 4 + wave;        // chunk index
    if (c >= C) return;
    const int base = c * CHUNK + 4 * lane;

    const float sh = shift[0];

    const int4   id4 = *(const int4*)(ray_id + base);
    const float4 dd  = *(const float4*)(density + base);
    const float4* rp = (const float4*)(rgb_raw + 3 * base);
    const float4 c0 = rp[0], c1 = rp[1], c2 = rp[2];

    // boundary flags (chunk start is a piece boundary by construction, not a flag)
    const int  pid = dpp_movi<0x138, 0xf>(id4.w, 0);   // prev lane's last id
    const bool f0 = (lane != 0) && (id4.x != pid);
    const bool f1 = (id4.y != id4.x);
    const bool f2 = (id4.z != id4.y);
    const bool f3 = (id4.w != id4.z);

    const float om0 = __builtin_amdgcn_rsqf(1.0f + __expf(dd.x + sh));
    const float om1 = __builtin_amdgcn_rsqf(1.0f + __expf(dd.y + sh));
    const float om2 = __builtin_amdgcn_rsqf(1.0f + __expf(dd.z + sh));
    const float om3 = __builtin_amdgcn_rsqf(1.0f + __expf(dd.w + sh));
    const float al0 = 1.0f - om0, al1 = 1.0f - om1;
    const float al2 = 1.0f - om2, al3 = 1.0f - om3;

    // sigmoids: sample k channels (rgb_raw[3i+j] layout, same as R0)
    const float g00 = sigm(c0.x), g01 = sigm(c0.y), g02 = sigm(c0.z);
    const float g10 = sigm(c0.w), g11 = sigm(c1.x), g12 = sigm(c1.y);
    const float g20 = sigm(c1.z), g21 = sigm(c1.w), g22 = sigm(c2.x);
    const float g30 = sigm(c2.y), g31 = sigm(c2.z), g32 = sigm(c2.w);

    // ---- pass 1: per-lane segmented affine summary (suffix since last cut)
    Seg a; a.p = 1.0f; a.s0 = 0.0f; a.s1 = 0.0f; a.s2 = 0.0f; a.f = 0;
#define P1(fk, alk, omk, ga, gb, gc)                                          \
    if (fk) { a.p = 1.0f; a.s0 = 0.0f; a.s1 = 0.0f; a.s2 = 0.0f; a.f = 1; }   \
    { const float t = a.p * alk;                                              \
      a.s0 = fmaf(t, ga, a.s0); a.s1 = fmaf(t, gb, a.s1);                     \
      a.s2 = fmaf(t, gc, a.s2); a.p *= omk; }
    P1(f0, al0, om0, g00, g01, g02)
    P1(f1, al1, om1, g10, g11, g12)
    P1(f2, al2, om2, g20, g21, g22)
    P1(f3, al3, om3, g30, g31, g32)
#undef P1

    // ---- wave inclusive segmented scan (DPP network) ----------------------
    seg_step<0x111, 0xf>(a);   // row_shr:1
    seg_step<0x112, 0xf>(a);   // row_shr:2
    seg_step<0x114, 0xf>(a);   // row_shr:4
    seg_step<0x118, 0xf>(a);   // row_shr:8
    seg_step<0x142, 0xa>(a);   // row_bcast:15 -> rows 1,3
    seg_step<0x143, 0xc>(a);   // row_bcast:31 -> rows 2,3

    // ---- exclusive carries: wave_shr:1 with identity at lane 0 ------------
    const float pe  = dpp_movf<0x138, 0xf>(a.p, 1.0f);
    const float se0 = dpp_movf<0x138, 0xf>(a.s0, 0.0f);
    const float se1 = dpp_movf<0x138, 0xf>(a.s1, 0.0f);
    const float se2 = dpp_movf<0x138, 0xf>(a.s2, 0.0f);
    const int   fe  = dpp_movi<0x138, 0xf>(a.f, 0);

    // ---- pass 2: per-sample walk with carries; emit complete rays ---------
    float T = pe, r0 = se0, r1 = se1, r2 = se2;
    bool sb = (fe != 0);        // a boundary has occurred before this point
    int prev = pid;             // id of sample preceding this lane (unused on lane 0)
#define P2(fk, idk, alk, omk, ga, gb, gc)                                     \
    if (fk) {                                                                 \
        if (sb) { float* o = out + 3 * prev;                                  \
                  o[0] = r0 + T; o[1] = r1 + T; o[2] = r2 + T; }              \
        else    { head[c] = make_float4(r0, r1, r2, T); }                     \
        for (int rr = prev + 1; rr < idk; ++rr) {                             \
            float* o = out + 3 * rr; o[0] = 1.0f; o[1] = 1.0f; o[2] = 1.0f; } \
        T = 1.0f; r0 = 0.0f; r1 = 0.0f; r2 = 0.0f; sb = true;                 \
    }                                                                         \
    { const float w = T * alk;                                                \
      r0 = fmaf(w, ga, r0); r1 = fmaf(w, gb, r1); r2 = fmaf(w, gc, r2);       \
      T *= omk; prev = idk; }
    P2(f0, id4.x, al0, om0, g00, g01, g02)
    P2(f1, id4.y, al1, om1, g10, g11, g12)
    P2(f2, id4.z, al2, om2, g20, g21, g22)
    P2(f3, id4.w, al3, om3, g30, g31, g32)
#undef P2

    // tail record: lane 63's running state = last piece of the chunk
    if (lane == 63) tail[c] = make_float4(r0, r1, r2, T);
    const int lastid = __builtin_amdgcn_readlane(id4.w, 63);
    if (lane == 0) ids[c] = make_int2(id4.x, lastid);
}

__global__ __launch_bounds__(256) void stitch_kernel(
    const int2*   __restrict__ ids,
    const float4* __restrict__ head,
    const float4* __restrict__ tail,
    float* __restrict__ out,
    int C, int N)
{
    const int b = blockIdx.x * 256 + threadIdx.x;
    if (b > C) return;

    if (b == 0) {
        const int rc = ids[0].x;
        for (int rr = 0; rr < rc; ++rr) {           // empty rays before first
            float* o = out + 3 * rr; o[0] = 1.0f; o[1] = 1.0f; o[2] = 1.0f;
        }
        if (ids[0].y != rc) {   // first ray starts at global start, ends inside chunk 0
            const float4 h = head[0];
            float* o = out + 3 * rc;
            o[0] = h.x + h.w; o[1] = h.y + h.w; o[2] = h.z + h.w;
        }
        return;
    }

    float cs0, cs1, cs2, cp;
    int r, j;
    if (b == C) {
        r = ids[C - 1].y;                            // ends at global end
        cs0 = cs1 = cs2 = 0.0f; cp = 1.0f; j = C - 1;
        for (int rr = r + 1; rr < N; ++rr) {         // empty rays after last
            float* o = out + 3 * rr; o[0] = 1.0f; o[1] = 1.0f; o[2] = 1.0f;
        }
    } else {
        const int rp_ = ids[b - 1].y, rc_ = ids[b].x;
        if (rp_ == rc_) {
            r = rc_;
            if (ids[b].y == r) return;               // continues past chunk b: later thread
            const float4 h = head[b];                // ends strictly inside chunk b
            cs0 = h.x; cs1 = h.y; cs2 = h.z; cp = h.w; j = b - 1;
        } else {
            r = rp_;                                 // rp_ ended exactly at end of chunk b-1
            cs0 = cs1 = cs2 = 0.0f; cp = 1.0f; j = b - 1;
            for (int rr = rp_ + 1; rr < rc_; ++rr) { // empty rays in the gap
                float* o = out + 3 * rr; o[0] = 1.0f; o[1] = 1.0f; o[2] = 1.0f;
            }
            if (ids[b].y != rc_) {  // rc_ starts at chunk b start, ends inside b
                const float4 h = head[b];
                float* o = out + 3 * rc_;
                o[0] = h.x + h.w; o[1] = h.y + h.w; o[2] = h.z + h.w;
            }
        }
    }

    // backward walk over tail/full pieces: cs = S_j + P_j*cs ; cp *= P_j
    while (j >= 0 && ids[j].y == r) {
        const float4 t = tail[j];
        cs0 = fmaf(t.w, cs0, t.x);
        cs1 = fmaf(t.w, cs1, t.y);
        cs2 = fmaf(t.w, cs2, t.z);
        cp *= t.w;
        if (ids[j].x != r) break;                    // started within chunk j
        if (j == 0) break;
        if (ids[j - 1].y != r) break;                // started exactly at chunk j start
        j--;
    }
    float* o = out + 3 * r;
    o[0] = cs0 + cp; o[1] = cs1 + cp; o[2] = cs2 + cp;
}

extern "C" void kernel_launch(void* const* d_in, const int* in_sizes, int n_in,
                              void* d_out, int out_size, void* d_ws, size_t ws_size,
                              hipStream_t stream)
{
    const float* density = (const float*)d_in[0];
    const float* rgb_raw = (const float*)d_in[1];
    const float* shift   = (const float*)d_in[2];
    const int*   ray_id  = (const int*)d_in[3];
    float* out = (float*)d_out;

    const int M = in_sizes[0];
    const int N = out_size / 3;
    const int C = M / CHUNK;                 // M = 4194304 -> 16384 chunks

    int2*   ids  = (int2*)d_ws;
    float4* head = (float4*)((char*)d_ws + (((size_t)C * sizeof(int2) + 255) & ~(size_t)255));
    float4* tail = head + C;

    const int blocks = (C + 3) / 4;          // 4 wave-chunks per 256-thread block
    march_dense_kernel<<<blocks, 256, 0, stream>>>(density, rgb_raw, shift,
                                                   ray_id, out, ids, head, tail, C);
    stitch_kernel<<<(C + 1 + 255) / 256, 256, 0, stream>>>(ids, head, tail, out, C, N);
}